// Round 1
// baseline (566.625 us; speedup 1.0000x reference)
//
#include <hip/hip_runtime.h>
#include <math.h>

#define CUTOFF   513
#define NFRAMES  4095
#define TLEN     2097152
#define NBATCH   16
#define NW       4    // waves per block
#define MTS      17   // mag-tile row stride in floats (513 rows x 16 frames, +1 pad)

// compiler barrier + drain this wave's LDS ops (FFT phase is wave-private)
#define WAVE_SYNC() asm volatile("s_waitcnt lgkmcnt(0)" ::: "memory")

__device__ __forceinline__ float2 cadd(float2 a, float2 b){return make_float2(a.x+b.x, a.y+b.y);}
__device__ __forceinline__ float2 csub(float2 a, float2 b){return make_float2(a.x-b.x, a.y-b.y);}
__device__ __forceinline__ float2 cmul(float2 a, float2 b){return make_float2(a.x*b.x-a.y*b.y, a.x*b.y+a.y*b.x);}
__device__ __forceinline__ float2 cmul_mi(float2 a){return make_float2(a.y, -a.x);}  // *(-i)

// natural-order in/out 16-point DFT (W16 = e^{-2pi i/16}), fully in registers
__device__ __forceinline__ void fft16(float2* A) {
    const float C1 = 0.92387953251f, S1 = 0.38268343236f, HF = 0.70710678119f;
    float2 C[16];
    #pragma unroll
    for (int j4 = 0; j4 < 4; ++j4) {
        float2 a = A[j4], b = A[j4+4], c = A[j4+8], d = A[j4+12];
        float2 t0 = cadd(a,c), t1 = csub(a,c), t2 = cadd(b,d), t3 = csub(b,d);
        C[4*j4+0] = cadd(t0,t2);
        C[4*j4+1] = make_float2(t1.x + t3.y, t1.y - t3.x);   // t1 - i*t3
        C[4*j4+2] = csub(t0,t2);
        C[4*j4+3] = make_float2(t1.x - t3.y, t1.y + t3.x);   // t1 + i*t3
    }
    C[4*1+1] = cmul(C[4*1+1], make_float2( C1,-S1));
    C[4*1+2] = cmul(C[4*1+2], make_float2( HF,-HF));
    C[4*1+3] = cmul(C[4*1+3], make_float2( S1,-C1));
    C[4*2+1] = cmul(C[4*2+1], make_float2( HF,-HF));
    C[4*2+2] = cmul_mi(C[4*2+2]);                             // W16^4 = -i
    C[4*2+3] = cmul(C[4*2+3], make_float2(-HF,-HF));
    C[4*3+1] = cmul(C[4*3+1], make_float2( S1,-C1));
    C[4*3+2] = cmul(C[4*3+2], make_float2(-HF,-HF));
    C[4*3+3] = cmul(C[4*3+3], make_float2(-C1, S1));          // W16^9
    #pragma unroll
    for (int klo = 0; klo < 4; ++klo) {
        float2 a = C[klo], b = C[4+klo], c = C[8+klo], d = C[12+klo];
        float2 t0 = cadd(a,c), t1 = csub(a,c), t2 = cadd(b,d), t3 = csub(b,d);
        A[klo]    = cadd(t0,t2);
        A[klo+4]  = make_float2(t1.x + t3.y, t1.y - t3.x);
        A[klo+8]  = csub(t0,t2);
        A[klo+12] = make_float2(t1.x - t3.y, t1.y + t3.x);
    }
}

// X[k3] = sum_{j2} h[j2] W4^{j2 k3}
__device__ __forceinline__ void dft4(const float2* h, float2* X) {
    float2 t0 = cadd(h[0],h[2]), t1 = csub(h[0],h[2]);
    float2 t2 = cadd(h[1],h[3]), t3 = csub(h[1],h[3]);
    X[0] = cadd(t0,t2);
    X[1] = make_float2(t1.x + t3.y, t1.y - t3.x);
    X[2] = csub(t0,t2);
    X[3] = make_float2(t1.x - t3.y, t1.y + t3.x);
}

// Hermitian unpack of packed pair at (Z_k, Z_{1024-k}) -> (|A_k|, |B_k|)
__device__ __forceinline__ float2 magpair(float2 Zk, float2 Zm) {
    float ax = Zk.x + Zm.x, ay = Zk.y - Zm.y;
    float bx = Zk.x - Zm.x, by = Zk.y + Zm.y;
    return make_float2(0.5f*sqrtf(ax*ax + ay*ay), 0.5f*sqrtf(bx*bx + by*by));
}

__global__ __launch_bounds__(256, 4)
void stft_mag_kernel(const float* __restrict__ in, float* __restrict__ out) {
    // Aliased LDS: phase 1 uses it as per-wave FFT workspace fftb[NW][1024] float2
    // (8192 floats); phase 2 reuses it as the 513 x 16 mag transpose tile with
    // row stride MTS=17 (8721 floats). Max = 34884 B -> 4 blocks/CU.
    __shared__ __align__(16) float sraw[513 * MTS + 15];
    const int tid = threadIdx.x, lane = tid & 63, w = tid >> 6;
    const int blk = blockIdx.x, b = blockIdx.y;
    const float* bi = in + (size_t)b * TLEN;
    float* bo = out + (size_t)b * ((size_t)CUTOFF * NFRAMES);
    float2* buf = (float2*)sraw + 1024 * w;
    float* mt = sraw;

    // magnitudes held in registers across the aliasing barrier
    float mags[2][16];
    float m512[2][2];

    #pragma unroll
    for (int r = 0; r < 2; ++r) {
        const int p = 8 * blk + 4 * r + w;          // pair -> frames 2p, 2p+1
        const bool noB = (2 * p + 1) >= NFRAMES;    // only pair 2047

        // ---- load: lane j holds x[64t + j]; z = frameA + i*frameB
        float v[24];
        const float* src = bi + 1024 * p + lane;
        #pragma unroll
        for (int t = 0; t < 16; ++t) v[t] = src[64 * t];
        #pragma unroll
        for (int t = 16; t < 24; ++t) v[t] = noB ? 0.f : src[64 * t];
        float2 A[16];
        #pragma unroll
        for (int rr = 0; rr < 16; ++rr) A[rr] = make_float2(v[rr], noB ? 0.f : v[rr + 8]);

        // ---- stage A: FFT-16 over r, then T1 twiddle W1024^{lane*k1}
        fft16(A);
        {
            float s, c;
            __sincosf((float)lane * 6.135923151542565e-03f, &s, &c);
            float2 w1 = make_float2(c, -s), t = make_float2(1.f, 0.f);
            #pragma unroll
            for (int k = 1; k < 16; ++k) { t = cmul(t, w1); A[k] = cmul(A[k], t); }
        }
        // transpose 1: addr(k1, j) = 64*k1 + ((j + 4*k1) & 63)
        #pragma unroll
        for (int k = 0; k < 16; ++k)
            buf[64 * k + ((lane + 4 * k) & 63)] = A[k];
        WAVE_SYNC();

        // ---- stage B: lane = (k1, j2); FFT-16; T2 twiddle W64^{j2*k2}
        const int k1 = lane & 15, j2 = lane >> 4;
        #pragma unroll
        for (int rr = 0; rr < 16; ++rr)
            A[rr] = buf[64 * k1 + ((4 * rr + j2 + 4 * k1) & 63)];
        fft16(A);
        {
            float s, c;
            __sincosf((float)j2 * 9.817477042468103e-02f, &s, &c);
            float2 w1 = make_float2(c, -s), t = make_float2(1.f, 0.f);
            #pragma unroll
            for (int k = 1; k < 16; ++k) { t = cmul(t, w1); A[k] = cmul(A[k], t); }
        }
        WAVE_SYNC();   // all lanes' stage-B reads drained before in-place overwrite
        // transpose 2: quartet q = k1+16*k2 at float2 base 4*sq, sq = q^(q>>4).
        // Half-swap swizzle e = bit2(sq): the two 16B halves of each quartet are
        // stored at 32*sq + 16*(half ^ e), making the b128 read quad-index
        // (2*sq+e)&7 a bijection of sq%8 -> conflict-free readout b128s.
        #pragma unroll
        for (int k = 0; k < 16; ++k) {
            int sv = k1 ^ k;                 // low 4 bits of sq (k2 = k)
            int eo = (sv >> 2) & 1;
            buf[64 * k + 4 * sv + 2 * ((j2 >> 1) ^ eo) + (j2 & 1)] = A[k];
        }
        WAVE_SYNC();

        // ---- readout into registers: 128 units; lane handles u = 2*lane, 2*lane+1.
        const float4* q4 = (const float4*)buf;
        #pragma unroll
        for (int vv = 0; vv < 2; ++vv) {
            const int u = 2 * lane + vv;
            if (u == 0) {
                // quartets 0 (sq=0,e=0) and 128 (sq=136,e=0)
                float4 a0 = q4[0], a1 = q4[1];
                float4 b0 = q4[272], b1 = q4[273];
                float2 hq[4] = {{a0.x,a0.y},{a0.z,a0.w},{a1.x,a1.y},{a1.z,a1.w}};
                float2 hp[4] = {{b0.x,b0.y},{b0.z,b0.w},{b1.x,b1.y},{b1.z,b1.w}};
                float2 X0[4], X1[4];
                dft4(hq, X0); dft4(hp, X1);
                mags[r][0] = fabsf(X0[0].x); mags[r][1] = fabsf(X0[0].y);   // row 0
                float2 m = magpair(X0[1], X0[3]);
                mags[r][2] = m.x; mags[r][3] = m.y;                          // row 256
                m512[r][0] = fabsf(X0[2].x); m512[r][1] = fabsf(X0[2].y);    // row 512
                m = magpair(X1[0], X1[3]);
                mags[r][4] = m.x; mags[r][5] = m.y;                          // row 128
                m = magpair(X1[1], X1[2]);
                mags[r][6] = m.x; mags[r][7] = m.y;                          // row 384
            } else {
                const int qq = u, qp = 256 - u;
                const int sq = qq ^ (qq >> 4), sp = qp ^ (qp >> 4);
                const int eq = (sq >> 2) & 1,  ep = (sp >> 2) & 1;
                float4 a0 = q4[2*sq + eq], a1 = q4[2*sq + 1 - eq];
                float4 b0 = q4[2*sp + ep], b1 = q4[2*sp + 1 - ep];
                float2 hq[4] = {{a0.x,a0.y},{a0.z,a0.w},{a1.x,a1.y},{a1.z,a1.w}};
                float2 hp[4] = {{b0.x,b0.y},{b0.z,b0.w},{b1.x,b1.y},{b1.z,b1.w}};
                float2 Xq[4], Xp[4];
                dft4(hq, Xq); dft4(hp, Xp);
                float2 m;
                m = magpair(Xq[0], Xp[3]);
                mags[r][8*vv+0] = m.x; mags[r][8*vv+1] = m.y;   // row u
                m = magpair(Xq[1], Xp[2]);
                mags[r][8*vv+2] = m.x; mags[r][8*vv+3] = m.y;   // row u+256
                m = magpair(Xp[0], Xq[3]);
                mags[r][8*vv+4] = m.x; mags[r][8*vv+5] = m.y;   // row 256-u
                m = magpair(Xp[1], Xq[2]);
                mags[r][8*vv+6] = m.x; mags[r][8*vv+7] = m.y;   // row 512-u
            }
        }
        WAVE_SYNC();   // q4 reads drained before next round overwrites buf
    }
    __syncthreads();   // all waves done with fftb region -> mt may alias it

    // ---- mag-tile writes (rows c, 16 frames/row, stride MTS)
    #pragma unroll
    for (int r = 0; r < 2; ++r) {
        const int f0 = 8 * r + 2 * w;   // block-local frames f0 (A), f0+1 (B)
        #pragma unroll
        for (int vv = 0; vv < 2; ++vv) {
            const int u = 2 * lane + vv;
            if (u == 0) {
                mt[MTS*0   + f0] = mags[r][0]; mt[MTS*0   + f0+1] = mags[r][1];
                mt[MTS*256 + f0] = mags[r][2]; mt[MTS*256 + f0+1] = mags[r][3];
                mt[MTS*128 + f0] = mags[r][4]; mt[MTS*128 + f0+1] = mags[r][5];
                mt[MTS*384 + f0] = mags[r][6]; mt[MTS*384 + f0+1] = mags[r][7];
                mt[MTS*512 + f0] = m512[r][0]; mt[MTS*512 + f0+1] = m512[r][1];
            } else {
                const int bse = 8 * vv;
                mt[MTS*u         + f0] = mags[r][bse+0]; mt[MTS*u         + f0+1] = mags[r][bse+1];
                mt[MTS*(u + 256) + f0] = mags[r][bse+2]; mt[MTS*(u + 256) + f0+1] = mags[r][bse+3];
                mt[MTS*(256 - u) + f0] = mags[r][bse+4]; mt[MTS*(256 - u) + f0+1] = mags[r][bse+5];
                mt[MTS*(512 - u) + f0] = mags[r][bse+6]; mt[MTS*(512 - u) + f0+1] = mags[r][bse+7];
            }
        }
    }
    __syncthreads();

    // ---- flush: 513 rows x 16 frames, 64B runs per row
    #pragma unroll
    for (int i = 0; i < 33; ++i) {
        int L = 256 * i + tid;
        if (L < 513 * 16) {
            int c = L >> 4, f = L & 15;
            int n = 16 * blk + f;
            if (n < NFRAMES)
                bo[(size_t)c * NFRAMES + n] = mt[MTS * c + f];
        }
    }
}

extern "C" void kernel_launch(void* const* d_in, const int* in_sizes, int n_in,
                              void* d_out, int out_size, void* d_ws, size_t ws_size,
                              hipStream_t stream) {
    const float* in = (const float*)d_in[0];   // (16, 2097152) fp32
    // d_in[1] (forward_basis) unused: it is exactly the DFT matrix; computed as FFT here.
    float* out = (float*)d_out;                // (16, 513, 4095) fp32
    dim3 grid(256, NBATCH, 1);                 // 256 blocks * 16 frames >= 4095
    stft_mag_kernel<<<grid, 256, 0, stream>>>(in, out);
}

// Round 2
// 255.717 us; speedup vs baseline: 2.2158x; 2.2158x over previous
//
#include <hip/hip_runtime.h>
#include <math.h>

#define CUTOFF   513
#define NFRAMES  4095
#define TLEN     2097152
#define NBATCH   16
#define NW       4   // waves per block; each wave: one packed pair-FFT (2 frames)

// compiler barrier + drain this wave's LDS ops (FFT phase is wave-private)
#define WAVE_SYNC() asm volatile("s_waitcnt lgkmcnt(0)" ::: "memory")

__device__ __forceinline__ float2 cadd(float2 a, float2 b){return make_float2(a.x+b.x, a.y+b.y);}
__device__ __forceinline__ float2 csub(float2 a, float2 b){return make_float2(a.x-b.x, a.y-b.y);}
__device__ __forceinline__ float2 cmul(float2 a, float2 b){return make_float2(a.x*b.x-a.y*b.y, a.x*b.y+a.y*b.x);}
__device__ __forceinline__ float2 cmul_mi(float2 a){return make_float2(a.y, -a.x);}  // *(-i)

// natural-order in/out 16-point DFT (W16 = e^{-2pi i/16}), fully in registers
__device__ __forceinline__ void fft16(float2* A) {
    const float C1 = 0.92387953251f, S1 = 0.38268343236f, HF = 0.70710678119f;
    float2 C[16];
    #pragma unroll
    for (int j4 = 0; j4 < 4; ++j4) {
        float2 a = A[j4], b = A[j4+4], c = A[j4+8], d = A[j4+12];
        float2 t0 = cadd(a,c), t1 = csub(a,c), t2 = cadd(b,d), t3 = csub(b,d);
        C[4*j4+0] = cadd(t0,t2);
        C[4*j4+1] = make_float2(t1.x + t3.y, t1.y - t3.x);   // t1 - i*t3
        C[4*j4+2] = csub(t0,t2);
        C[4*j4+3] = make_float2(t1.x - t3.y, t1.y + t3.x);   // t1 + i*t3
    }
    // twiddle C[j4][klo] *= W16^{j4*klo}
    C[4*1+1] = cmul(C[4*1+1], make_float2( C1,-S1));
    C[4*1+2] = cmul(C[4*1+2], make_float2( HF,-HF));
    C[4*1+3] = cmul(C[4*1+3], make_float2( S1,-C1));
    C[4*2+1] = cmul(C[4*2+1], make_float2( HF,-HF));
    C[4*2+2] = cmul_mi(C[4*2+2]);                             // W16^4 = -i
    C[4*2+3] = cmul(C[4*2+3], make_float2(-HF,-HF));
    C[4*3+1] = cmul(C[4*3+1], make_float2( S1,-C1));
    C[4*3+2] = cmul(C[4*3+2], make_float2(-HF,-HF));
    C[4*3+3] = cmul(C[4*3+3], make_float2(-C1, S1));          // W16^9
    #pragma unroll
    for (int klo = 0; klo < 4; ++klo) {
        float2 a = C[klo], b = C[4+klo], c = C[8+klo], d = C[12+klo];
        float2 t0 = cadd(a,c), t1 = csub(a,c), t2 = cadd(b,d), t3 = csub(b,d);
        A[klo]    = cadd(t0,t2);
        A[klo+4]  = make_float2(t1.x + t3.y, t1.y - t3.x);
        A[klo+8]  = csub(t0,t2);
        A[klo+12] = make_float2(t1.x - t3.y, t1.y + t3.x);
    }
}

// X[k3] = sum_{j2} h[j2] W4^{j2 k3}
__device__ __forceinline__ void dft4(const float2* h, float2* X) {
    float2 t0 = cadd(h[0],h[2]), t1 = csub(h[0],h[2]);
    float2 t2 = cadd(h[1],h[3]), t3 = csub(h[1],h[3]);
    X[0] = cadd(t0,t2);
    X[1] = make_float2(t1.x + t3.y, t1.y - t3.x);
    X[2] = csub(t0,t2);
    X[3] = make_float2(t1.x - t3.y, t1.y + t3.x);
}

// Hermitian unpack of packed pair at (Z_k, Z_{1024-k}) -> (|A_k|, |B_k|)
__device__ __forceinline__ float2 magpair(float2 Zk, float2 Zm) {
    float ax = Zk.x + Zm.x, ay = Zk.y - Zm.y;
    float bx = Zk.x - Zm.x, by = Zk.y + Zm.y;
    return make_float2(0.5f*sqrtf(ax*ax + ay*ay), 0.5f*sqrtf(bx*bx + by*by));
}

__global__ __launch_bounds__(256, 4)
void stft_mag_kernel(const float* __restrict__ in, float* __restrict__ out) {
    __shared__ float2 fftb[NW][1024];   // 32 KB: per-wave four-step workspace
    __shared__ float  mt[256 * 8];      // 8 KB: HALF mag tile (256 rows x 8 frames)
    // total LDS = 40960 B -> exactly 4 blocks/CU
    const int tid = threadIdx.x, lane = tid & 63, w = tid >> 6;
    // XCD swizzle: hw id H -> xcd (H&7) owns a contiguous 1024-block chunk, so
    // line-sharing neighbor blocks (blk, blk^1) co-reside on one XCD's L2 and
    // their 32B half-line output writes merge before HBM eviction.
    const int H = blockIdx.x;
    const int LB = ((H & 7) << 10) | (H >> 3);
    const int b = LB >> 9, blk = LB & 511;
    const int p = 4 * blk + w;                 // pair 0..2047 -> frames 2p, 2p+1
    const bool noB = (2 * p + 1) >= NFRAMES;   // only pair 2047
    const float* bi = in + (size_t)b * TLEN;
    float* bo = out + (size_t)b * ((size_t)CUTOFF * NFRAMES);
    float2* buf = fftb[w];

    // ---- load: lane j holds x[64r + j]; z = frameA + i*frameB, frameB[e]=frameA[e+512]
    float v[24];
    const float* src = bi + 1024 * p + lane;
    #pragma unroll
    for (int t = 0; t < 16; ++t) v[t] = src[64 * t];
    #pragma unroll
    for (int t = 16; t < 24; ++t) v[t] = noB ? 0.f : src[64 * t];
    float2 A[16];
    #pragma unroll
    for (int r = 0; r < 16; ++r) A[r] = make_float2(v[r], noB ? 0.f : v[r + 8]);

    // ---- stage A: FFT-16 over r, then T1 twiddle W1024^{lane*k1}
    fft16(A);
    {
        float s, c;
        __sincosf((float)lane * 6.135923151542565e-03f, &s, &c);
        float2 w1 = make_float2(c, -s), t = make_float2(1.f, 0.f);
        #pragma unroll
        for (int k = 1; k < 16; ++k) { t = cmul(t, w1); A[k] = cmul(A[k], t); }
    }
    // transpose 1: addr(k1, j) = 64*k1 + ((j + 4*k1) & 63)
    #pragma unroll
    for (int k = 0; k < 16; ++k)
        buf[64 * k + ((lane + 4 * k) & 63)] = A[k];
    WAVE_SYNC();

    // ---- stage B: lane = (k1 = lane&15, j2 = lane>>4); FFT-16 over j1; T2 W64^{j2*k2}
    const int k1 = lane & 15, j2 = lane >> 4;
    #pragma unroll
    for (int r = 0; r < 16; ++r)
        A[r] = buf[64 * k1 + ((4 * r + j2 + 4 * k1) & 63)];
    fft16(A);
    {
        float s, c;
        __sincosf((float)j2 * 9.817477042468103e-02f, &s, &c);
        float2 w1 = make_float2(c, -s), t = make_float2(1.f, 0.f);
        #pragma unroll
        for (int k = 1; k < 16; ++k) { t = cmul(t, w1); A[k] = cmul(A[k], t); }
    }
    WAVE_SYNC();   // all lanes' stage-B reads drained before in-place overwrite
    // transpose 2: quartet q = k1+16*k2 at float2 base 4*sq, sq = q^(q>>4).
    // Half-swap swizzle e = bit2(sq): the two 16B halves of each quartet are
    // stored at 32*sq + 16*(half ^ e), making the b128 read quad-index
    // (2*sq+e)&7 a bijection of sq%8 -> 2-way (free) instead of 4-way reads.
    #pragma unroll
    for (int k = 0; k < 16; ++k) {
        int sv = k1 ^ k;                 // low 4 bits of sq (k2 = k)
        int eo = (sv >> 2) & 1;
        buf[64 * k + 4 * sv + 2 * ((j2 >> 1) ^ eo) + (j2 & 1)] = A[k];
    }
    WAVE_SYNC();

    // ---- readout: 128 units; lane handles u = 2*lane, 2*lane+1.
    // Chunk0 rows (0..255) written to mt now; chunk1 rows (256..511, stored as
    // local row-256) kept in 8 regs; row 512 written direct to global.
    const int f0 = 2 * w;   // block-local frames: f0 (A), f0+1 (B)
    const float4* q4 = (const float4*)buf;
    float ch1[8];
    auto MTW = [&](int k, int f, float val) {   // k = row within current chunk
        mt[8 * k + ((f + (k >> 3)) & 7)] = val;
    };
    #pragma unroll
    for (int vv = 0; vv < 2; ++vv) {
        const int u = 2 * lane + vv;
        if (u == 0) {
            float4 a0 = q4[0], a1 = q4[1];           // sq=0, e=0
            float4 b0 = q4[272], b1 = q4[273];       // q=128: sq=136, e=0
            float2 hq[4] = {{a0.x,a0.y},{a0.z,a0.w},{a1.x,a1.y},{a1.z,a1.w}};
            float2 hp[4] = {{b0.x,b0.y},{b0.z,b0.w},{b1.x,b1.y},{b1.z,b1.w}};
            float2 X0[4], X1[4];
            dft4(hq, X0); dft4(hp, X1);
            // chunk0: rows 0, 128
            MTW(0, f0, fabsf(X0[0].x)); MTW(0, f0 + 1, fabsf(X0[0].y));
            float2 m = magpair(X1[0], X1[3]);
            MTW(128, f0, m.x); MTW(128, f0 + 1, m.y);
            // chunk1: global rows 256, 384 -> local 0, 128
            m = magpair(X0[1], X0[3]); ch1[0] = m.x; ch1[1] = m.y;
            m = magpair(X1[1], X1[2]); ch1[2] = m.x; ch1[3] = m.y;
            // row 512 direct
            bo[(size_t)512 * NFRAMES + 2 * p] = fabsf(X0[2].x);
            if (!noB) bo[(size_t)512 * NFRAMES + 2 * p + 1] = fabsf(X0[2].y);
        } else {
            const int q = u, qp = 256 - u;
            const int sq = q ^ (q >> 4), sp = qp ^ (qp >> 4);
            const int eq = (sq >> 2) & 1,  ep = (sp >> 2) & 1;
            float4 a0 = q4[2*sq + eq], a1 = q4[2*sq + 1 - eq];
            float4 b0 = q4[2*sp + ep], b1 = q4[2*sp + 1 - ep];
            float2 hq[4] = {{a0.x,a0.y},{a0.z,a0.w},{a1.x,a1.y},{a1.z,a1.w}};
            float2 hp[4] = {{b0.x,b0.y},{b0.z,b0.w},{b1.x,b1.y},{b1.z,b1.w}};
            float2 Xq[4], Xp[4];
            dft4(hq, Xq); dft4(hp, Xp);
            float2 m;
            // chunk0: rows u, 256-u
            m = magpair(Xq[0], Xp[3]); MTW(u,       f0, m.x); MTW(u,       f0+1, m.y);
            m = magpair(Xp[0], Xq[3]); MTW(256 - u, f0, m.x); MTW(256 - u, f0+1, m.y);
            // chunk1: global rows u+256, 512-u -> local u, 256-u
            m = magpair(Xq[1], Xp[2]); ch1[4*vv+0] = m.x; ch1[4*vv+1] = m.y;
            m = magpair(Xp[1], Xq[2]); ch1[4*vv+2] = m.x; ch1[4*vv+3] = m.y;
        }
    }
    __syncthreads();

    // ---- flush chunk0: rows c=0..255, 8 frames/row (32B runs)
    #pragma unroll
    for (int i = 0; i < 8; ++i) {
        int L = 256 * i + tid;
        int c = L >> 3, f = L & 7;
        int n = 8 * blk + f;
        if (n < NFRAMES)
            bo[(size_t)c * NFRAMES + n] = mt[8 * c + ((f + (c >> 3)) & 7)];
    }
    __syncthreads();

    // ---- chunk1 tile writes from regs
    #pragma unroll
    for (int vv = 0; vv < 2; ++vv) {
        const int u = 2 * lane + vv;
        if (u == 0) {
            MTW(0,   f0, ch1[0]); MTW(0,   f0 + 1, ch1[1]);
            MTW(128, f0, ch1[2]); MTW(128, f0 + 1, ch1[3]);
        } else {
            MTW(u,       f0, ch1[4*vv+0]); MTW(u,       f0+1, ch1[4*vv+1]);
            MTW(256 - u, f0, ch1[4*vv+2]); MTW(256 - u, f0+1, ch1[4*vv+3]);
        }
    }
    __syncthreads();

    // ---- flush chunk1: global rows 256..511
    #pragma unroll
    for (int i = 0; i < 8; ++i) {
        int L = 256 * i + tid;
        int c = L >> 3, f = L & 7;
        int n = 8 * blk + f;
        if (n < NFRAMES)
            bo[(size_t)(256 + c) * NFRAMES + n] = mt[8 * c + ((f + (c >> 3)) & 7)];
    }
}

extern "C" void kernel_launch(void* const* d_in, const int* in_sizes, int n_in,
                              void* d_out, int out_size, void* d_ws, size_t ws_size,
                              hipStream_t stream) {
    const float* in = (const float*)d_in[0];   // (16, 2097152) fp32
    // d_in[1] (forward_basis) unused: it is exactly the DFT matrix; computed as FFT here.
    float* out = (float*)d_out;                // (16, 513, 4095) fp32
    dim3 grid(512 * NBATCH, 1, 1);             // 8192 blocks, xcd-swizzled in-kernel
    stft_mag_kernel<<<grid, 256, 0, stream>>>(in, out);
}

// Round 3
// 242.846 us; speedup vs baseline: 2.3333x; 1.0530x over previous
//
#include <hip/hip_runtime.h>
#include <math.h>

#define CUTOFF   513
#define NFRAMES  4095
#define TLEN     2097152
#define NBATCH   16
#define NW       4   // waves per block; each wave: one packed pair-FFT (2 frames)

// compiler barrier + drain this wave's LDS ops (FFT phase is wave-private)
#define WAVE_SYNC() asm volatile("s_waitcnt lgkmcnt(0)" ::: "memory")

// complex number in a VGPR pair: .x = real (lo), .y = imag (hi)
typedef float cplx __attribute__((ext_vector_type(2)));

// ---- packed fp32 complex primitives (VOP3P: 1-2 insts instead of 2-4 scalar)
__device__ __forceinline__ cplx cadd(cplx a, cplx b){
    cplx r; asm("v_pk_add_f32 %0, %1, %2" : "=v"(r) : "v"(a), "v"(b)); return r;
}
__device__ __forceinline__ cplx csub(cplx a, cplx b){
    cplx r; asm("v_pk_add_f32 %0, %1, %2 op_sel:[0,0] op_sel_hi:[1,1] neg_lo:[0,1] neg_hi:[0,1]"
                : "=v"(r) : "v"(a), "v"(b)); return r;
}
// a - i*b = (a.x + b.y, a.y - b.x)
__device__ __forceinline__ cplx submul_i(cplx a, cplx b){
    cplx r; asm("v_pk_add_f32 %0, %1, %2 op_sel:[0,1] op_sel_hi:[1,0] neg_hi:[0,1]"
                : "=v"(r) : "v"(a), "v"(b)); return r;
}
// a + i*b = (a.x - b.y, a.y + b.x)
__device__ __forceinline__ cplx addmul_i(cplx a, cplx b){
    cplx r; asm("v_pk_add_f32 %0, %1, %2 op_sel:[0,1] op_sel_hi:[1,0] neg_lo:[0,1]"
                : "=v"(r) : "v"(a), "v"(b)); return r;
}
// full complex multiply: (ax*bx - ay*by, ax*by + ay*bx), 2 packed insts
__device__ __forceinline__ cplx cmul(cplx a, cplx b){
    cplx t, r;
    asm("v_pk_mul_f32 %0, %1, %2 op_sel:[1,1] op_sel_hi:[1,0]"
        : "=v"(t) : "v"(a), "v"(b));                       // (ay*by, ay*bx)
    asm("v_pk_fma_f32 %0, %1, %2, %3 op_sel:[0,0,0] op_sel_hi:[0,1,1] neg_lo:[0,0,1]"
        : "=v"(r) : "v"(a), "v"(b), "v"(t));               // (ax*bx - ay*by, ax*by + ay*bx)
    return r;
}
__device__ __forceinline__ cplx cmul_mi(cplx a){ return (cplx){a.y, -a.x}; }  // *(-i)

// natural-order in/out 16-point DFT (W16 = e^{-2pi i/16}), fully in registers
__device__ __forceinline__ void fft16(cplx* A) {
    const float C1 = 0.92387953251f, S1 = 0.38268343236f, HF = 0.70710678119f;
    cplx C[16];
    #pragma unroll
    for (int j4 = 0; j4 < 4; ++j4) {
        cplx a = A[j4], b = A[j4+4], c = A[j4+8], d = A[j4+12];
        cplx t0 = cadd(a,c), t1 = csub(a,c), t2 = cadd(b,d), t3 = csub(b,d);
        C[4*j4+0] = cadd(t0,t2);
        C[4*j4+1] = submul_i(t1,t3);
        C[4*j4+2] = csub(t0,t2);
        C[4*j4+3] = addmul_i(t1,t3);
    }
    // twiddle C[j4][klo] *= W16^{j4*klo}
    C[4*1+1] = cmul(C[4*1+1], (cplx){ C1,-S1});
    C[4*1+2] = cmul(C[4*1+2], (cplx){ HF,-HF});
    C[4*1+3] = cmul(C[4*1+3], (cplx){ S1,-C1});
    C[4*2+1] = cmul(C[4*2+1], (cplx){ HF,-HF});
    C[4*2+2] = cmul_mi(C[4*2+2]);                             // W16^4 = -i
    C[4*2+3] = cmul(C[4*2+3], (cplx){-HF,-HF});
    C[4*3+1] = cmul(C[4*3+1], (cplx){ S1,-C1});
    C[4*3+2] = cmul(C[4*3+2], (cplx){-HF,-HF});
    C[4*3+3] = cmul(C[4*3+3], (cplx){-C1, S1});               // W16^9
    #pragma unroll
    for (int klo = 0; klo < 4; ++klo) {
        cplx a = C[klo], b = C[4+klo], c = C[8+klo], d = C[12+klo];
        cplx t0 = cadd(a,c), t1 = csub(a,c), t2 = cadd(b,d), t3 = csub(b,d);
        A[klo]    = cadd(t0,t2);
        A[klo+4]  = submul_i(t1,t3);
        A[klo+8]  = csub(t0,t2);
        A[klo+12] = addmul_i(t1,t3);
    }
}

// X[k3] = sum_{j2} h[j2] W4^{j2 k3}
__device__ __forceinline__ void dft4(const cplx* h, cplx* X) {
    cplx t0 = cadd(h[0],h[2]), t1 = csub(h[0],h[2]);
    cplx t2 = cadd(h[1],h[3]), t3 = csub(h[1],h[3]);
    X[0] = cadd(t0,t2);
    X[1] = submul_i(t1,t3);
    X[2] = csub(t0,t2);
    X[3] = addmul_i(t1,t3);
}

// Hermitian unpack of packed pair at (Z_k, Z_{1024-k}) -> (|A_k|, |B_k|)
__device__ __forceinline__ float2 magpair(cplx Zk, cplx Zm) {
    cplx xs, ys, s;
    // xs = (Zk.x+Zm.x, Zk.x-Zm.x)
    asm("v_pk_add_f32 %0, %1, %2 op_sel:[0,0] op_sel_hi:[0,0] neg_hi:[0,1]"
        : "=v"(xs) : "v"(Zk), "v"(Zm));
    // ys = (Zk.y-Zm.y, Zk.y+Zm.y)
    asm("v_pk_add_f32 %0, %1, %2 op_sel:[1,1] op_sel_hi:[1,1] neg_lo:[0,1]"
        : "=v"(ys) : "v"(Zk), "v"(Zm));
    asm("v_pk_mul_f32 %0, %1, %1" : "=v"(s) : "v"(xs));
    asm("v_pk_fma_f32 %0, %1, %1, %2" : "=v"(s) : "v"(ys), "v"(s));
    return make_float2(0.5f*sqrtf(s.x), 0.5f*sqrtf(s.y));
}

__global__ __launch_bounds__(256, 4)
void stft_mag_kernel(const float* __restrict__ in, float* __restrict__ out) {
    __shared__ __align__(16) cplx fftb[NW][1024];   // 32 KB: per-wave four-step workspace
    __shared__ float  mt[256 * 8];                  // 8 KB: HALF mag tile (256 rows x 8 frames)
    // total LDS = 40960 B -> exactly 4 blocks/CU
    const int tid = threadIdx.x, lane = tid & 63, w = tid >> 6;
    // XCD swizzle: hw id H -> xcd (H&7) owns a contiguous 1024-block chunk, so
    // line-sharing neighbor blocks (blk, blk^1) co-reside on one XCD's L2 and
    // their 32B half-line output writes merge before HBM eviction.
    const int H = blockIdx.x;
    const int LB = ((H & 7) << 10) | (H >> 3);
    const int b = LB >> 9, blk = LB & 511;
    const int p = 4 * blk + w;                 // pair 0..2047 -> frames 2p, 2p+1
    const bool noB = (2 * p + 1) >= NFRAMES;   // only pair 2047
    const float* bi = in + (size_t)b * TLEN;
    float* bo = out + (size_t)b * ((size_t)CUTOFF * NFRAMES);
    cplx* buf = fftb[w];

    // ---- load: lane j holds x[64r + j]; z = frameA + i*frameB, frameB[e]=frameA[e+512]
    float v[24];
    const float* src = bi + 1024 * p + lane;
    #pragma unroll
    for (int t = 0; t < 16; ++t) v[t] = src[64 * t];
    #pragma unroll
    for (int t = 16; t < 24; ++t) v[t] = noB ? 0.f : src[64 * t];
    cplx A[16];
    #pragma unroll
    for (int r = 0; r < 16; ++r) A[r] = (cplx){v[r], noB ? 0.f : v[r + 8]};

    // ---- stage A: FFT-16 over r, then T1 twiddle W1024^{lane*k1}
    fft16(A);
    {
        float s, c;
        __sincosf((float)lane * 6.135923151542565e-03f, &s, &c);
        cplx w1 = (cplx){c, -s}, t = (cplx){1.f, 0.f};
        #pragma unroll
        for (int k = 1; k < 16; ++k) { t = cmul(t, w1); A[k] = cmul(A[k], t); }
    }
    // transpose 1: addr(k1, j) = 64*k1 + ((j + 4*k1) & 63)
    #pragma unroll
    for (int k = 0; k < 16; ++k)
        buf[64 * k + ((lane + 4 * k) & 63)] = A[k];
    WAVE_SYNC();

    // ---- stage B: lane = (k1 = lane&15, j2 = lane>>4); FFT-16 over j1; T2 W64^{j2*k2}
    const int k1 = lane & 15, j2 = lane >> 4;
    #pragma unroll
    for (int r = 0; r < 16; ++r)
        A[r] = buf[64 * k1 + ((4 * r + j2 + 4 * k1) & 63)];
    fft16(A);
    {
        float s, c;
        __sincosf((float)j2 * 9.817477042468103e-02f, &s, &c);
        cplx w1 = (cplx){c, -s}, t = (cplx){1.f, 0.f};
        #pragma unroll
        for (int k = 1; k < 16; ++k) { t = cmul(t, w1); A[k] = cmul(A[k], t); }
    }
    WAVE_SYNC();   // all lanes' stage-B reads drained before in-place overwrite
    // transpose 2: quartet q = k1+16*k2 at float2 base 4*sq, sq = q^(q>>4).
    // Half-swap swizzle e = bit2(sq): the two 16B halves of each quartet are
    // stored at 32*sq + 16*(half ^ e), making the b128 read quad-index
    // (2*sq+e)&7 a bijection of sq%8 -> 2-way (free) instead of 4-way reads.
    #pragma unroll
    for (int k = 0; k < 16; ++k) {
        int sv = k1 ^ k;                 // low 4 bits of sq (k2 = k)
        int eo = (sv >> 2) & 1;
        buf[64 * k + 4 * sv + 2 * ((j2 >> 1) ^ eo) + (j2 & 1)] = A[k];
    }
    WAVE_SYNC();

    // ---- readout: 128 units; lane handles u = 2*lane, 2*lane+1.
    // Chunk0 rows (0..255) written to mt now; chunk1 rows (256..511, stored as
    // local row-256) kept in 8 regs; row 512 written direct to global.
    const int f0 = 2 * w;   // block-local frames: f0 (A), f0+1 (B)
    const float4* q4 = (const float4*)buf;
    float ch1[8];
    auto MTW = [&](int k, int f, float val) {   // k = row within current chunk
        mt[8 * k + ((f + (k >> 3)) & 7)] = val;
    };
    #pragma unroll
    for (int vv = 0; vv < 2; ++vv) {
        const int u = 2 * lane + vv;
        if (u == 0) {
            float4 a0 = q4[0], a1 = q4[1];           // sq=0, e=0
            float4 b0 = q4[272], b1 = q4[273];       // q=128: sq=136, e=0
            cplx hq[4], hp[4];
            hq[0]=(cplx){a0.x,a0.y}; hq[1]=(cplx){a0.z,a0.w}; hq[2]=(cplx){a1.x,a1.y}; hq[3]=(cplx){a1.z,a1.w};
            hp[0]=(cplx){b0.x,b0.y}; hp[1]=(cplx){b0.z,b0.w}; hp[2]=(cplx){b1.x,b1.y}; hp[3]=(cplx){b1.z,b1.w};
            cplx X0[4], X1[4];
            dft4(hq, X0); dft4(hp, X1);
            // chunk0: rows 0, 128
            MTW(0, f0, fabsf(X0[0].x)); MTW(0, f0 + 1, fabsf(X0[0].y));
            float2 m = magpair(X1[0], X1[3]);
            MTW(128, f0, m.x); MTW(128, f0 + 1, m.y);
            // chunk1: global rows 256, 384 -> local 0, 128
            m = magpair(X0[1], X0[3]); ch1[0] = m.x; ch1[1] = m.y;
            m = magpair(X1[1], X1[2]); ch1[2] = m.x; ch1[3] = m.y;
            // row 512 direct
            bo[(size_t)512 * NFRAMES + 2 * p] = fabsf(X0[2].x);
            if (!noB) bo[(size_t)512 * NFRAMES + 2 * p + 1] = fabsf(X0[2].y);
        } else {
            const int q = u, qp = 256 - u;
            const int sq = q ^ (q >> 4), sp = qp ^ (qp >> 4);
            const int eq = (sq >> 2) & 1,  ep = (sp >> 2) & 1;
            float4 a0 = q4[2*sq + eq], a1 = q4[2*sq + 1 - eq];
            float4 b0 = q4[2*sp + ep], b1 = q4[2*sp + 1 - ep];
            cplx hq[4], hp[4];
            hq[0]=(cplx){a0.x,a0.y}; hq[1]=(cplx){a0.z,a0.w}; hq[2]=(cplx){a1.x,a1.y}; hq[3]=(cplx){a1.z,a1.w};
            hp[0]=(cplx){b0.x,b0.y}; hp[1]=(cplx){b0.z,b0.w}; hp[2]=(cplx){b1.x,b1.y}; hp[3]=(cplx){b1.z,b1.w};
            cplx Xq[4], Xp[4];
            dft4(hq, Xq); dft4(hp, Xp);
            float2 m;
            // chunk0: rows u, 256-u
            m = magpair(Xq[0], Xp[3]); MTW(u,       f0, m.x); MTW(u,       f0+1, m.y);
            m = magpair(Xp[0], Xq[3]); MTW(256 - u, f0, m.x); MTW(256 - u, f0+1, m.y);
            // chunk1: global rows u+256, 512-u -> local u, 256-u
            m = magpair(Xq[1], Xp[2]); ch1[4*vv+0] = m.x; ch1[4*vv+1] = m.y;
            m = magpair(Xp[1], Xq[2]); ch1[4*vv+2] = m.x; ch1[4*vv+3] = m.y;
        }
    }
    __syncthreads();

    // ---- flush chunk0: rows c=0..255, 8 frames/row (32B runs)
    #pragma unroll
    for (int i = 0; i < 8; ++i) {
        int L = 256 * i + tid;
        int c = L >> 3, f = L & 7;
        int n = 8 * blk + f;
        if (n < NFRAMES)
            bo[(size_t)c * NFRAMES + n] = mt[8 * c + ((f + (c >> 3)) & 7)];
    }
    __syncthreads();

    // ---- chunk1 tile writes from regs
    #pragma unroll
    for (int vv = 0; vv < 2; ++vv) {
        const int u = 2 * lane + vv;
        if (u == 0) {
            MTW(0,   f0, ch1[0]); MTW(0,   f0 + 1, ch1[1]);
            MTW(128, f0, ch1[2]); MTW(128, f0 + 1, ch1[3]);
        } else {
            MTW(u,       f0, ch1[4*vv+0]); MTW(u,       f0+1, ch1[4*vv+1]);
            MTW(256 - u, f0, ch1[4*vv+2]); MTW(256 - u, f0+1, ch1[4*vv+3]);
        }
    }
    __syncthreads();

    // ---- flush chunk1: global rows 256..511
    #pragma unroll
    for (int i = 0; i < 8; ++i) {
        int L = 256 * i + tid;
        int c = L >> 3, f = L & 7;
        int n = 8 * blk + f;
        if (n < NFRAMES)
            bo[(size_t)(256 + c) * NFRAMES + n] = mt[8 * c + ((f + (c >> 3)) & 7)];
    }
}

extern "C" void kernel_launch(void* const* d_in, const int* in_sizes, int n_in,
                              void* d_out, int out_size, void* d_ws, size_t ws_size,
                              hipStream_t stream) {
    const float* in = (const float*)d_in[0];   // (16, 2097152) fp32
    // d_in[1] (forward_basis) unused: it is exactly the DFT matrix; computed as FFT here.
    float* out = (float*)d_out;                // (16, 513, 4095) fp32
    dim3 grid(512 * NBATCH, 1, 1);             // 8192 blocks, xcd-swizzled in-kernel
    stft_mag_kernel<<<grid, 256, 0, stream>>>(in, out);
}